// Round 1
// baseline (5958.880 us; speedup 1.0000x reference)
//
#include <hip/hip_runtime.h>
#include <hip/hip_fp16.h>
#include <cstdint>

#define EPSQ 1e-6f
#define E_LAM 1e-4f

#define B_ 256
#define S_ 512
#define F_ 16
#define C1_ 64
#define C2_ 128
#define C3_ 256
#define HID_ 128

// ---------------- init min/max slots ----------------
__global__ void k_init(unsigned int* mm){
  int t = threadIdx.x;
  if (t < 4) mm[t] = (t & 1) ? 0u : 0x7f800000u;  // min=+inf, max=0 (all values >0)
}

// ---------------- queue layer phase 1: raw W_q/L_q + global min/max ----------------
__global__ __launch_bounds__(256) void k_queue1(
    const float* __restrict__ x, const float* __restrict__ ksp, const float* __restrict__ kap,
    float* __restrict__ Wq, float* __restrict__ Lq, unsigned int* __restrict__ mm){
  int i = blockIdx.x * 256 + threadIdx.x;           // i in [0, B*S)
  float ks = ksp[0], ka = kap[0];
  float dist = x[(size_t)i*F_ + 13];                // x[:,:,-3]
  float air  = x[(size_t)i*F_ + 11];                // x[:,:,-5]
  float ES  = ks*dist + EPSQ;
  float lam = ka/(air + EPSQ);
  float rho = fminf(lam*ES, 0.99f);
  float wq  = rho/(1.0f - rho + EPSQ)*ES;
  float lq  = lam*wq;
  Wq[i] = wq; Lq[i] = lq;
  float wmin=wq, wmax=wq, lmin=lq, lmax=lq;
  for (int o=32;o;o>>=1){
    wmin = fminf(wmin, __shfl_xor(wmin,o));
    wmax = fmaxf(wmax, __shfl_xor(wmax,o));
    lmin = fminf(lmin, __shfl_xor(lmin,o));
    lmax = fmaxf(lmax, __shfl_xor(lmax,o));
  }
  if ((threadIdx.x & 63) == 0){                     // positive floats: uint order == float order
    atomicMin(mm+0, __float_as_uint(wmin));
    atomicMax(mm+1, __float_as_uint(wmax));
    atomicMin(mm+2, __float_as_uint(lmin));
    atomicMax(mm+3, __float_as_uint(lmax));
  }
}

// ---------------- queue layer phase 2: normalize in-place + per-batch means ----------------
__global__ __launch_bounds__(256) void k_queue2(
    float* __restrict__ Wq, float* __restrict__ Lq, const unsigned int* __restrict__ mm,
    float* __restrict__ dbar, float* __restrict__ lbar){
  int b = blockIdx.x, t = threadIdx.x;
  float minW = __uint_as_float(mm[0]), maxW = __uint_as_float(mm[1]);
  float minL = __uint_as_float(mm[2]), maxL = __uint_as_float(mm[3]);
  float dW = maxW - minW + EPSQ;
  float dL = maxL - minL + EPSQ;
  float sw = 0.f, sl = 0.f;
  for (int s=t; s<S_; s+=256){
    size_t idx = (size_t)b*S_ + s;
    float wn = (Wq[idx]-minW)/dW;
    float ln = (Lq[idx]-minL)/dL;
    Wq[idx]=wn; Lq[idx]=ln;
    sw += wn; sl += ln;
  }
  for (int o=32;o;o>>=1){ sw += __shfl_xor(sw,o); sl += __shfl_xor(sl,o); }
  __shared__ float rs[4], rl[4];
  int w = t>>6;
  if ((t&63)==0){ rs[w]=sw; rl[w]=sl; }
  __syncthreads();
  if (t==0){
    dbar[b] = (rs[0]+rs[1]+rs[2]+rs[3]) * (1.0f/S_);
    lbar[b] = (rl[0]+rl[1]+rl[2]+rl[3]) * (1.0f/S_);
  }
}

// ---------------- conv weight repack: w[co][ci][k] -> wr[ci][k][co] ----------------
__global__ void k_repack_conv(const float* __restrict__ w, float* __restrict__ wr, int CIN, int COUT){
  int idx = blockIdx.x*256 + threadIdx.x;
  int N = CIN*COUT*3;
  if (idx >= N) return;
  int co = idx % COUT;
  int r  = idx / COUT;
  int k  = r % 3;
  int ci = r / 3;
  wr[idx] = w[((size_t)co*CIN + ci)*3 + k];
}

// ---------------- LSTM weight repack to transposed f16-pairs + fused bias ----------------
__global__ void k_repack_lstm(
    const float* __restrict__ mod_w, const float* __restrict__ w_ih, const float* __restrict__ w_hh,
    const float* __restrict__ b_ih, const float* __restrict__ b_hh,
    __half2* __restrict__ mw2, __half2* __restrict__ wih2, __half2* __restrict__ whh2,
    float* __restrict__ biasg){
  int idx = blockIdx.x*256 + threadIdx.x;
  const int N1 = 65*256, N2 = 128*512, N3 = 64*512;
  if (idx < N1){
    int i2 = idx >> 8, j = idx & 255;     // mw2[i2][j] = (mod_w[j][2i2], mod_w[j][2i2+1])
    mw2[idx] = __floats2half2_rn(mod_w[j*130 + 2*i2], mod_w[j*130 + 2*i2 + 1]);
  } else if (idx < N1+N2){
    int t = idx - N1;
    int j2 = t >> 9, k = t & 511;         // wih2[j2][k] = (w_ih[k][2j2], w_ih[k][2j2+1])
    wih2[t] = __floats2half2_rn(w_ih[(size_t)k*256 + 2*j2], w_ih[(size_t)k*256 + 2*j2+1]);
  } else if (idx < N1+N2+N3){
    int t = idx - N1 - N2;
    int i2 = t >> 9, k = t & 511;         // whh2[i2][k]
    whh2[t] = __floats2half2_rn(w_hh[(size_t)k*128 + 2*i2], w_hh[(size_t)k*128 + 2*i2+1]);
  } else if (idx < N1+N2+N3+512){
    int k = idx - N1-N2-N3;
    biasg[k] = b_ih[k] + b_hh[k];
  }
}

// ---------------- conv1d(k=3,SAME) + bias + relu ----------------
// block: 256 threads. co = tid%COUT, sg = tid/COUT; each thread does 8 s-positions.
// TOUT=0: out (B,COUT,S);  TOUT=1: out (B,S,COUT) (transposed, lane-coalesced store)
template<int CIN, int COUT, int TOUT>
__global__ __launch_bounds__(256) void k_conv(
    const float* __restrict__ in, const float* __restrict__ wr,
    const float* __restrict__ bias, float* __restrict__ out){
  constexpr int SG    = 256/COUT;
  constexpr int STILE = SG*8;
  constexpr int RS    = STILE+4;   // padded row stride (mult of 4 floats -> 16B aligned rows)
  __shared__ __align__(16) float lds[CIN*RS];
  int b = blockIdx.y;
  int s_base = blockIdx.x * STILE;
  int tid = threadIdx.x;
  if (CIN == F_){
    // input is x (B,S,F): transpose into LDS
    for (int idx=tid; idx<CIN*(STILE+2); idx+=256){
      int ci = idx & (F_-1);
      int sp = idx >> 4;
      int sg = s_base - 1 + sp;
      float v = (sg>=0 && sg<S_) ? in[((size_t)b*S_+sg)*F_ + ci] : 0.0f;
      lds[ci*RS+sp] = v;
    }
  } else {
    // input is z (B,CIN,S)
    for (int idx=tid; idx<CIN*(STILE+2); idx+=256){
      int sp = idx % (STILE+2);
      int ci = idx / (STILE+2);
      int sg = s_base - 1 + sp;
      float v = (sg>=0 && sg<S_) ? in[((size_t)b*CIN+ci)*S_ + sg] : 0.0f;
      lds[ci*RS+sp] = v;
    }
  }
  __syncthreads();
  int co = tid % COUT;
  int sg = tid / COUT;
  int s0 = sg*8;
  float acc[8] = {0,0,0,0,0,0,0,0};
  for (int ci=0; ci<CIN; ci++){
    const float* w = &wr[(ci*3)*COUT + co];
    float w0=w[0], w1=w[COUT], w2=w[2*COUT];
    const float* r = &lds[ci*RS + s0];
    float4 va = *(const float4*)(r);
    float4 vb = *(const float4*)(r+4);
    float2 vc = *(const float2*)(r+8);
    float v[10] = {va.x,va.y,va.z,va.w, vb.x,vb.y,vb.z,vb.w, vc.x,vc.y};
    #pragma unroll
    for (int ss=0; ss<8; ss++) acc[ss] += w0*v[ss] + w1*v[ss+1] + w2*v[ss+2];
  }
  float bb = bias[co];
  if (!TOUT){
    float* o = &out[((size_t)b*COUT+co)*S_ + s_base + s0];
    float4 o0 = make_float4(fmaxf(acc[0]+bb,0.f), fmaxf(acc[1]+bb,0.f), fmaxf(acc[2]+bb,0.f), fmaxf(acc[3]+bb,0.f));
    float4 o1 = make_float4(fmaxf(acc[4]+bb,0.f), fmaxf(acc[5]+bb,0.f), fmaxf(acc[6]+bb,0.f), fmaxf(acc[7]+bb,0.f));
    *(float4*)(o)   = o0;
    *(float4*)(o+4) = o1;
  } else {
    #pragma unroll
    for (int ss=0; ss<8; ss++)
      out[((size_t)b*S_ + s_base+s0+ss)*COUT + co] = fmaxf(acc[ss]+bb, 0.0f);
  }
}

// ---------------- SimAM for (B,C,S) layout: one block per (b,c) row ----------------
__global__ __launch_bounds__(256) void k_simam1(
    float* __restrict__ z, const float* __restrict__ dbar, const float* __restrict__ lbar, int C){
  int bid = blockIdx.x;
  int b = bid / C, c = bid % C;
  float* row = z + ((size_t)b*C + c)*S_;
  int t = threadIdx.x;
  float v0 = row[t], v1 = row[t+256];
  float s = v0+v1, q = v0*v0 + v1*v1;
  for (int o=32;o;o>>=1){ s += __shfl_xor(s,o); q += __shfl_xor(q,o); }
  __shared__ float rs[4], rq[4];
  int w = t>>6;
  if ((t&63)==0){ rs[w]=s; rq[w]=q; }
  __syncthreads();
  float st = rs[0]+rs[1]+rs[2]+rs[3];
  float qt = rq[0]+rq[1]+rq[2]+rq[3];
  float mu  = st*(1.0f/S_);
  float var = qt*(1.0f/S_) - mu*mu;
  float e = var + dbar[b] + 0.5f*lbar[b] + E_LAM;
  float g = 1.0f/(1.0f + expf(-e));
  row[t] = v0*g; row[t+256] = v1*g;
}

// ---------------- SimAM for (B,S,C3) layout: one block per batch ----------------
__global__ __launch_bounds__(1024) void k_simam2(
    float* __restrict__ zt, const float* __restrict__ dbar, const float* __restrict__ lbar){
  int b = blockIdx.x;
  int tid = threadIdx.x;
  int c = tid & 255, part = tid >> 8;      // 4 partitions x 128 timesteps
  float* base = zt + ((size_t)b*S_ + part*128)*C3_ + c;
  float s=0.f, q=0.f;
  #pragma unroll 4
  for (int i=0;i<128;i++){ float v = base[(size_t)i*C3_]; s+=v; q+=v*v; }
  __shared__ float S4[4][256], Q4[4][256], gate[256];
  S4[part][c]=s; Q4[part][c]=q;
  __syncthreads();
  if (part==0){
    float st = S4[0][c]+S4[1][c]+S4[2][c]+S4[3][c];
    float qt = Q4[0][c]+Q4[1][c]+Q4[2][c]+Q4[3][c];
    float mu  = st*(1.0f/S_);
    float var = qt*(1.0f/S_) - mu*mu;
    float e = var + dbar[b] + 0.5f*lbar[b] + E_LAM;
    gate[c] = 1.0f/(1.0f+expf(-e));
  }
  __syncthreads();
  float g = gate[c];
  #pragma unroll 4
  for (int i=0;i<128;i++) base[(size_t)i*C3_] *= g;
}

// ---------------- Mogrifier-LSTM: one block per batch, 512 steps in-kernel ----------------
__global__ __launch_bounds__(256) void k_lstm(
    const float* __restrict__ zt, const float* __restrict__ Wn, const float* __restrict__ Ln,
    const __half2* __restrict__ mw2, const float* __restrict__ mod_b,
    const __half2* __restrict__ wih2, const __half2* __restrict__ whh2,
    const float* __restrict__ biasg, const float* __restrict__ cls_w, const float* __restrict__ cls_b,
    float* __restrict__ out){
  int b = blockIdx.x, tid = threadIdx.x;
  __shared__ __align__(16) float h_s[128];
  __shared__ __align__(16) float ms_s[256];
  __shared__ __align__(16) float g_s[512];
  const float2* h2  = (const float2*)h_s;
  const float2* ms2 = (const float2*)ms_s;
  float c = 0.0f;
  if (tid < 128) h_s[tid] = 0.0f;
  float mb  = mod_b[tid];
  float bg0 = biasg[tid], bg1 = biasg[tid+256];
  const float* ztb = zt + (size_t)b*S_*C3_;
  const float* wnb = Wn + (size_t)b*S_;
  const float* lnb = Ln + (size_t)b*S_;
  __syncthreads();
  for (int t=0; t<S_; t++){
    float dt = wnb[t], lt = lnb[t];
    // ---- mogrifier gate m (thread j = tid) ----
    float acc = mb;
    #pragma unroll 8
    for (int i2=0;i2<64;i2++){
      float2 w = __half22float2(mw2[i2*256+tid]);
      float2 h = h2[i2];
      acc += h.x*w.x + h.y*w.y;
    }
    {
      float2 w = __half22float2(mw2[64*256+tid]);  // rows 128(d),129(l)
      acc += dt*w.x + lt*w.y;
    }
    float m = 1.0f/(1.0f+expf(-acc));
    ms_s[tid] = m * ztb[(size_t)t*C3_ + tid];
    __syncthreads();
    // ---- g = (m*s) @ Wih^T + h @ Whh^T + bias (threads own k=tid, tid+256) ----
    float a0 = bg0, a1 = bg1;
    #pragma unroll 8
    for (int j2=0;j2<128;j2++){
      float2 v  = ms2[j2];
      float2 w0 = __half22float2(wih2[j2*512+tid]);
      float2 w1 = __half22float2(wih2[j2*512+tid+256]);
      a0 += v.x*w0.x + v.y*w0.y;
      a1 += v.x*w1.x + v.y*w1.y;
    }
    #pragma unroll 8
    for (int i2=0;i2<64;i2++){
      float2 h  = h2[i2];
      float2 w0 = __half22float2(whh2[i2*512+tid]);
      float2 w1 = __half22float2(whh2[i2*512+tid+256]);
      a0 += h.x*w0.x + h.y*w0.y;
      a1 += h.x*w1.x + h.y*w1.y;
    }
    g_s[tid] = a0; g_s[tid+256] = a1;
    __syncthreads();
    // ---- state update (threads 0..127) ----
    if (tid < 128){
      float ig=g_s[tid], fg=g_s[128+tid], gg=g_s[256+tid], og=g_s[384+tid];
      float sf = 1.0f/(1.0f+expf(-fg));
      float si = 1.0f/(1.0f+expf(-ig));
      float so = 1.0f/(1.0f+expf(-og));
      c = sf*c + si*tanhf(gg);
      h_s[tid] = so*tanhf(c);
    }
    __syncthreads();
  }
  // ---- classifier fused: out[b,:8] ----
  if (tid < 8){
    float a = cls_b[tid];
    #pragma unroll 8
    for (int i=0;i<HID_;i++) a += h_s[i]*cls_w[tid*HID_+i];
    out[b*8+tid] = a;
  }
}

extern "C" void kernel_launch(void* const* d_in, const int* in_sizes, int n_in,
                              void* d_out, int out_size, void* d_ws, size_t ws_size,
                              hipStream_t stream){
  const float* x     = (const float*)d_in[0];
  const float* k_s   = (const float*)d_in[1];
  const float* k_a   = (const float*)d_in[2];
  const float* w1    = (const float*)d_in[3];
  const float* b1    = (const float*)d_in[4];
  const float* w2    = (const float*)d_in[5];
  const float* b2    = (const float*)d_in[6];
  const float* w3    = (const float*)d_in[7];
  const float* b3    = (const float*)d_in[8];
  const float* mod_w = (const float*)d_in[9];
  const float* mod_b = (const float*)d_in[10];
  const float* w_ih  = (const float*)d_in[11];
  const float* w_hh  = (const float*)d_in[12];
  const float* b_ih  = (const float*)d_in[13];
  const float* b_hh  = (const float*)d_in[14];
  const float* cls_w = (const float*)d_in[15];
  const float* cls_b = (const float*)d_in[16];
  float* outp = (float*)d_out;

  char* ws = (char*)d_ws;
  size_t o = 0;
  auto alloc = [&](size_t bytes){ size_t r = o; o = (o + bytes + 255) & ~(size_t)255; return r; };
  float*        Wq   = (float*)(ws + alloc((size_t)B_*S_*4));
  float*        Lq   = (float*)(ws + alloc((size_t)B_*S_*4));
  unsigned int* MM   = (unsigned int*)(ws + alloc(16));
  float*        DB   = (float*)(ws + alloc(B_*4));
  float*        LB   = (float*)(ws + alloc(B_*4));
  float*        WR1  = (float*)(ws + alloc((size_t)F_*3*C1_*4));
  float*        WR2  = (float*)(ws + alloc((size_t)C1_*3*C2_*4));
  float*        WR3  = (float*)(ws + alloc((size_t)C2_*3*C3_*4));
  __half2*      MW2  = (__half2*)(ws + alloc((size_t)65*256*4));
  __half2*      WIH2 = (__half2*)(ws + alloc((size_t)128*512*4));
  __half2*      WHH2 = (__half2*)(ws + alloc((size_t)64*512*4));
  float*        BG   = (float*)(ws + alloc(512*4));
  float*        Z1   = (float*)(ws + alloc((size_t)B_*C1_*S_*4));
  float*        Z2   = (float*)(ws + alloc((size_t)B_*C2_*S_*4));
  float*        ZT3  = (float*)(ws + alloc((size_t)B_*S_*C3_*4));
  (void)ws_size; (void)in_sizes; (void)n_in; (void)out_size;

  hipLaunchKernelGGL(k_init, dim3(1), dim3(64), 0, stream, MM);
  hipLaunchKernelGGL(k_queue1, dim3((B_*S_)/256), dim3(256), 0, stream, x, k_s, k_a, Wq, Lq, MM);
  hipLaunchKernelGGL(k_queue2, dim3(B_), dim3(256), 0, stream, Wq, Lq, MM, DB, LB);

  hipLaunchKernelGGL(k_repack_conv, dim3((F_*3*C1_+255)/256), dim3(256), 0, stream, w1, WR1, F_, C1_);
  hipLaunchKernelGGL(k_repack_conv, dim3((C1_*3*C2_+255)/256), dim3(256), 0, stream, w2, WR2, C1_, C2_);
  hipLaunchKernelGGL(k_repack_conv, dim3((C2_*3*C3_+255)/256), dim3(256), 0, stream, w3, WR3, C2_, C3_);
  {
    int N = 65*256 + 128*512 + 64*512 + 512;
    hipLaunchKernelGGL(k_repack_lstm, dim3((N+255)/256), dim3(256), 0, stream,
                       mod_w, w_ih, w_hh, b_ih, b_hh, MW2, WIH2, WHH2, BG);
  }

  hipLaunchKernelGGL((k_conv<F_, C1_, 0>), dim3(S_/32, B_), dim3(256), 0, stream, x,  WR1, b1, Z1);
  hipLaunchKernelGGL(k_simam1, dim3(B_*C1_), dim3(256), 0, stream, Z1, DB, LB, C1_);
  hipLaunchKernelGGL((k_conv<C1_, C2_, 0>), dim3(S_/16, B_), dim3(256), 0, stream, Z1, WR2, b2, Z2);
  hipLaunchKernelGGL(k_simam1, dim3(B_*C2_), dim3(256), 0, stream, Z2, DB, LB, C2_);
  hipLaunchKernelGGL((k_conv<C2_, C3_, 1>), dim3(S_/8, B_), dim3(256), 0, stream, Z2, WR3, b3, ZT3);
  hipLaunchKernelGGL(k_simam2, dim3(B_), dim3(1024), 0, stream, ZT3, DB, LB);

  hipLaunchKernelGGL(k_lstm, dim3(B_), dim3(256), 0, stream,
                     ZT3, Wq, Lq, MW2, mod_b, WIH2, WHH2, BG, cls_w, cls_b, outp);
}

// Round 2
// 2997.220 us; speedup vs baseline: 1.9881x; 1.9881x over previous
//
#include <hip/hip_runtime.h>
#include <hip/hip_fp16.h>
#include <cstdint>

#define EPSQ 1e-6f
#define E_LAM 1e-4f

#define B_ 256
#define S_ 512
#define F_ 16
#define C1_ 64
#define C2_ 128
#define C3_ 256
#define HID_ 128

typedef _Float16 f16x8 __attribute__((ext_vector_type(8)));
typedef _Float16 f16x4 __attribute__((ext_vector_type(4)));
typedef float f32x4 __attribute__((ext_vector_type(4)));

__device__ __forceinline__ float sigm(float x){
  return __builtin_amdgcn_rcpf(1.0f + __builtin_amdgcn_exp2f(-1.44269504f*x));
}
__device__ __forceinline__ float tanhft(float x){
  float e = __builtin_amdgcn_exp2f(-2.88539008f*x);
  return (1.0f - e) * __builtin_amdgcn_rcpf(1.0f + e);
}

// ---------------- init min/max slots ----------------
__global__ void k_init(unsigned int* mm){
  int t = threadIdx.x;
  if (t < 4) mm[t] = (t & 1) ? 0u : 0x7f800000u;  // min=+inf, max=0 (all values >0)
}

// ---------------- queue layer phase 1 ----------------
__global__ __launch_bounds__(256) void k_queue1(
    const float* __restrict__ x, const float* __restrict__ ksp, const float* __restrict__ kap,
    float* __restrict__ Wq, float* __restrict__ Lq, unsigned int* __restrict__ mm){
  int i = blockIdx.x * 256 + threadIdx.x;
  float ks = ksp[0], ka = kap[0];
  float dist = x[(size_t)i*F_ + 13];
  float air  = x[(size_t)i*F_ + 11];
  float ES  = ks*dist + EPSQ;
  float lam = ka/(air + EPSQ);
  float rho = fminf(lam*ES, 0.99f);
  float wq  = rho/(1.0f - rho + EPSQ)*ES;
  float lq  = lam*wq;
  Wq[i] = wq; Lq[i] = lq;
  float wmin=wq, wmax=wq, lmin=lq, lmax=lq;
  for (int o=32;o;o>>=1){
    wmin = fminf(wmin, __shfl_xor(wmin,o));
    wmax = fmaxf(wmax, __shfl_xor(wmax,o));
    lmin = fminf(lmin, __shfl_xor(lmin,o));
    lmax = fmaxf(lmax, __shfl_xor(lmax,o));
  }
  if ((threadIdx.x & 63) == 0){
    atomicMin(mm+0, __float_as_uint(wmin));
    atomicMax(mm+1, __float_as_uint(wmax));
    atomicMin(mm+2, __float_as_uint(lmin));
    atomicMax(mm+3, __float_as_uint(lmax));
  }
}

// ---------------- queue layer phase 2 ----------------
__global__ __launch_bounds__(256) void k_queue2(
    float* __restrict__ Wq, float* __restrict__ Lq, const unsigned int* __restrict__ mm,
    float* __restrict__ dbar, float* __restrict__ lbar){
  int b = blockIdx.x, t = threadIdx.x;
  float minW = __uint_as_float(mm[0]), maxW = __uint_as_float(mm[1]);
  float minL = __uint_as_float(mm[2]), maxL = __uint_as_float(mm[3]);
  float dW = maxW - minW + EPSQ;
  float dL = maxL - minL + EPSQ;
  float sw = 0.f, sl = 0.f;
  for (int s=t; s<S_; s+=256){
    size_t idx = (size_t)b*S_ + s;
    float wn = (Wq[idx]-minW)/dW;
    float ln = (Lq[idx]-minL)/dL;
    Wq[idx]=wn; Lq[idx]=ln;
    sw += wn; sl += ln;
  }
  for (int o=32;o;o>>=1){ sw += __shfl_xor(sw,o); sl += __shfl_xor(sl,o); }
  __shared__ float rs[4], rl[4];
  int w = t>>6;
  if ((t&63)==0){ rs[w]=sw; rl[w]=sl; }
  __syncthreads();
  if (t==0){
    dbar[b] = (rs[0]+rs[1]+rs[2]+rs[3]) * (1.0f/S_);
    lbar[b] = (rl[0]+rl[1]+rl[2]+rl[3]) * (1.0f/S_);
  }
}

// ---------------- conv weight repack: w[co][ci][k] -> wr[ci][k][co] ----------------
__global__ void k_repack_conv(const float* __restrict__ w, float* __restrict__ wr, int CIN, int COUT){
  int idx = blockIdx.x*256 + threadIdx.x;
  int N = CIN*COUT*3;
  if (idx >= N) return;
  int co = idx % COUT;
  int r  = idx / COUT;
  int k  = r % 3;
  int ci = r / 3;
  wr[idx] = w[((size_t)co*CIN + ci)*3 + k];
}

// ---------------- LSTM weight repack into MFMA A-fragments (f16) ----------------
// A-frag convention (16x16x32): lane l holds A[row = l&15][k = kk*32 + (l>>4)*8 + f], f=0..7
// flat idx for frag t (= nt*KK + kk): ((t*64 + l)*8 + f)
__global__ void k_repack_frags(
    const float* __restrict__ mod_w, const float* __restrict__ w_ih, const float* __restrict__ w_hh,
    const float* __restrict__ b_ih, const float* __restrict__ b_hh,
    __half* __restrict__ WIHf, __half* __restrict__ WHHf, __half* __restrict__ MWf,
    float* __restrict__ BG){
  int idx = blockIdx.x*256 + threadIdx.x;
  const int NIH = 32*8*512;   // 131072
  const int NHH = 32*4*512;   // 65536
  const int NMW = 16*5*512;   // 40960
  if (idx < NIH){
    int f = idx & 7, l = (idx>>3)&63; int t = idx>>9; int kk = t & 7; int nt = t>>3;
    int row = nt*16 + (l&15), k = kk*32 + ((l>>4)<<3) + f;
    WIHf[idx] = __float2half(w_ih[(size_t)row*256 + k]);
  } else if (idx < NIH+NHH){
    int j = idx - NIH;
    int f = j&7, l = (j>>3)&63; int t = j>>9; int kk = t&3; int nt = t>>2;
    int row = nt*16 + (l&15), k = kk*32 + ((l>>4)<<3) + f;
    WHHf[j] = __float2half(w_hh[(size_t)row*128 + k]);
  } else if (idx < NIH+NHH+NMW){
    int j = idx - NIH - NHH;
    int f = j&7, l = (j>>3)&63; int t = j>>9; int kk = t%5; int nt = t/5;
    int row = nt*16 + (l&15), k = kk*32 + ((l>>4)<<3) + f;
    float v = (k < 130) ? mod_w[(size_t)row*130 + k] : 0.0f;
    MWf[j] = __float2half(v);
  } else if (idx < NIH+NHH+NMW+512){
    int k = idx - NIH-NHH-NMW;
    BG[k] = b_ih[k] + b_hh[k];
  }
}

// ---------------- conv1d(k=3,SAME) + bias + relu ----------------
template<int CIN, int COUT, int TOUT>
__global__ __launch_bounds__(256) void k_conv(
    const float* __restrict__ in, const float* __restrict__ wr,
    const float* __restrict__ bias, float* __restrict__ out){
  constexpr int SG    = 256/COUT;
  constexpr int STILE = SG*8;
  constexpr int RS    = STILE+4;
  __shared__ __align__(16) float lds[CIN*RS];
  int b = blockIdx.y;
  int s_base = blockIdx.x * STILE;
  int tid = threadIdx.x;
  if (CIN == F_){
    for (int idx=tid; idx<CIN*(STILE+2); idx+=256){
      int ci = idx & (F_-1);
      int sp = idx >> 4;
      int sg = s_base - 1 + sp;
      float v = (sg>=0 && sg<S_) ? in[((size_t)b*S_+sg)*F_ + ci] : 0.0f;
      lds[ci*RS+sp] = v;
    }
  } else {
    for (int idx=tid; idx<CIN*(STILE+2); idx+=256){
      int sp = idx % (STILE+2);
      int ci = idx / (STILE+2);
      int sg = s_base - 1 + sp;
      float v = (sg>=0 && sg<S_) ? in[((size_t)b*CIN+ci)*S_ + sg] : 0.0f;
      lds[ci*RS+sp] = v;
    }
  }
  __syncthreads();
  int co = tid % COUT;
  int sg = tid / COUT;
  int s0 = sg*8;
  float acc[8] = {0,0,0,0,0,0,0,0};
  for (int ci=0; ci<CIN; ci++){
    const float* w = &wr[(ci*3)*COUT + co];
    float w0=w[0], w1=w[COUT], w2=w[2*COUT];
    const float* r = &lds[ci*RS + s0];
    float4 va = *(const float4*)(r);
    float4 vb = *(const float4*)(r+4);
    float2 vc = *(const float2*)(r+8);
    float v[10] = {va.x,va.y,va.z,va.w, vb.x,vb.y,vb.z,vb.w, vc.x,vc.y};
    #pragma unroll
    for (int ss=0; ss<8; ss++) acc[ss] += w0*v[ss] + w1*v[ss+1] + w2*v[ss+2];
  }
  float bb = bias[co];
  if (!TOUT){
    float* o = &out[((size_t)b*COUT+co)*S_ + s_base + s0];
    float4 o0 = make_float4(fmaxf(acc[0]+bb,0.f), fmaxf(acc[1]+bb,0.f), fmaxf(acc[2]+bb,0.f), fmaxf(acc[3]+bb,0.f));
    float4 o1 = make_float4(fmaxf(acc[4]+bb,0.f), fmaxf(acc[5]+bb,0.f), fmaxf(acc[6]+bb,0.f), fmaxf(acc[7]+bb,0.f));
    *(float4*)(o)   = o0;
    *(float4*)(o+4) = o1;
  } else {
    #pragma unroll
    for (int ss=0; ss<8; ss++)
      out[((size_t)b*S_ + s_base+s0+ss)*COUT + co] = fmaxf(acc[ss]+bb, 0.0f);
  }
}

// ---------------- SimAM (B,C,S) ----------------
__global__ __launch_bounds__(256) void k_simam1(
    float* __restrict__ z, const float* __restrict__ dbar, const float* __restrict__ lbar, int C){
  int bid = blockIdx.x;
  int b = bid / C, c = bid % C;
  float* row = z + ((size_t)b*C + c)*S_;
  int t = threadIdx.x;
  float v0 = row[t], v1 = row[t+256];
  float s = v0+v1, q = v0*v0 + v1*v1;
  for (int o=32;o;o>>=1){ s += __shfl_xor(s,o); q += __shfl_xor(q,o); }
  __shared__ float rs[4], rq[4];
  int w = t>>6;
  if ((t&63)==0){ rs[w]=s; rq[w]=q; }
  __syncthreads();
  float st = rs[0]+rs[1]+rs[2]+rs[3];
  float qt = rq[0]+rq[1]+rq[2]+rq[3];
  float mu  = st*(1.0f/S_);
  float var = qt*(1.0f/S_) - mu*mu;
  float e = var + dbar[b] + 0.5f*lbar[b] + E_LAM;
  float g = 1.0f/(1.0f + expf(-e));
  row[t] = v0*g; row[t+256] = v1*g;
}

// ---------------- SimAM (B,S,C3) ----------------
__global__ __launch_bounds__(1024) void k_simam2(
    float* __restrict__ zt, const float* __restrict__ dbar, const float* __restrict__ lbar){
  int b = blockIdx.x;
  int tid = threadIdx.x;
  int c = tid & 255, part = tid >> 8;
  float* base = zt + ((size_t)b*S_ + part*128)*C3_ + c;
  float s=0.f, q=0.f;
  #pragma unroll 4
  for (int i=0;i<128;i++){ float v = base[(size_t)i*C3_]; s+=v; q+=v*v; }
  __shared__ float S4[4][256], Q4[4][256], gate[256];
  S4[part][c]=s; Q4[part][c]=q;
  __syncthreads();
  if (part==0){
    float st = S4[0][c]+S4[1][c]+S4[2][c]+S4[3][c];
    float qt = Q4[0][c]+Q4[1][c]+Q4[2][c]+Q4[3][c];
    float mu  = st*(1.0f/S_);
    float var = qt*(1.0f/S_) - mu*mu;
    float e = var + dbar[b] + 0.5f*lbar[b] + E_LAM;
    gate[c] = 1.0f/(1.0f+expf(-e));
  }
  __syncthreads();
  float g = gate[c];
  #pragma unroll 4
  for (int i=0;i<128;i++) base[(size_t)i*C3_] *= g;
}

// ---------------- Mogrifier-LSTM via MFMA ----------------
// 16 blocks x 512 threads (8 waves). Block handles 16 batches.
// Operand-swapped: G^T[512x16] = Wih[512x256]@MS^T + Whh[512x128]@H^T (A=weights, B=activations).
// Wave w owns N-tiles {w, w+8, w+16, w+24} -> lane-local (i,f,g,o) -> register-only cell update.
__global__ __launch_bounds__(512, 2) void k_lstm_mfma(
    const float* __restrict__ zt, const float* __restrict__ Wn, const float* __restrict__ Ln,
    const __half* __restrict__ WIHf, const __half* __restrict__ WHHf, const __half* __restrict__ MWf,
    const float* __restrict__ mod_b, const float* __restrict__ BG,
    const float* __restrict__ cls_w, const float* __restrict__ cls_b, float* __restrict__ out){
  __shared__ __align__(16) __half MS_l[16*256];  // [batch][j] f16, rows 512B, XOR-swizzled
  __shared__ __align__(16) __half H_l[16*128];   // [batch][k] f16, rows 256B, XOR-swizzled
  const int tid = threadIdx.x;
  const int lane = tid & 63, w = tid >> 6;
  const int batch = lane & 15, kq = lane >> 4;
  const int b0 = blockIdx.x * 16;
  const int swz = (batch & 7) << 4;

  const f16x8* WIHv = (const f16x8*)WIHf;
  const f16x8* WHHv = (const f16x8*)WHHf;
  const f16x8* MWv  = (const f16x8*)MWf;

  // persistent A-frags: Whh (16) + mod_w (10)
  f16x8 whr[4][4];
  #pragma unroll
  for (int g=0; g<4; g++)
    #pragma unroll
    for (int kk=0; kk<4; kk++)
      whr[g][kk] = WHHv[(((w + g*8)*4 + kk)<<6) + lane];
  f16x8 mwr[2][5];
  #pragma unroll
  for (int i=0; i<2; i++)
    #pragma unroll
    for (int kk=0; kk<5; kk++)
      mwr[i][kk] = MWv[(((2*w + i)*5 + kk)<<6) + lane];

  f32x4 bgv[4], mbv[2];
  #pragma unroll
  for (int g=0; g<4; g++) bgv[g] = *(const f32x4*)(BG + g*128 + w*16 + kq*4);
  #pragma unroll
  for (int i=0; i<2; i++) mbv[i] = *(const f32x4*)(mod_b + (2*w + i)*16 + kq*4);

  for (int i=tid; i<1024; i+=512) ((unsigned int*)H_l)[i] = 0u;

  const float* zb  = zt + (size_t)(b0 + batch)*S_*C3_;
  const float* wnp = Wn + (size_t)(b0 + batch)*S_;
  const float* lnp = Ln + (size_t)(b0 + batch)*S_;

  f32x4 cst = {0.f,0.f,0.f,0.f};
  f32x4 hv  = {0.f,0.f,0.f,0.f};
  __syncthreads();

  f16x8 wb[3][4];  // Wih streaming ring
  for (int t=0; t<S_; t++){
    // defeat LICM of the per-step Wih streaming loads (we WANT re-load from L2)
    const f16x8* WIHp = WIHv;
    asm volatile("" : "+s"(WIHp));
    // prefetch Wih kk=0,1
    #pragma unroll
    for (int g=0; g<4; g++) wb[0][g] = WIHp[(((w + g*8)*8 + 0)<<6) + lane];
    #pragma unroll
    for (int g=0; g<4; g++) wb[1][g] = WIHp[(((w + g*8)*8 + 1)<<6) + lane];
    // inputs
    f32x4 zv0 = *(const f32x4*)(zb + t*C3_ + (2*w+0)*16 + kq*4);
    f32x4 zv1 = *(const f32x4*)(zb + t*C3_ + (2*w+1)*16 + kq*4);
    float dv = wnp[t], lv = lnp[t];
    // H b-frags (h_{t-1})
    f16x8 hb0[4];
    #pragma unroll
    for (int kk=0; kk<4; kk++)
      hb0[kk] = *(const f16x8*)((const char*)H_l + ((batch*256 + kk*64 + kq*16) ^ swz));
    f16x8 dlb = {0,0,0,0,0,0,0,0};
    if (kq == 0){ dlb[0] = (_Float16)dv; dlb[1] = (_Float16)lv; }
    // ---- mogrifier: Mg^T[256x16] ----
    f32x4 am0 = {0,0,0,0}, am1 = {0,0,0,0};
    #pragma unroll
    for (int kk=0; kk<4; kk++){
      am0 = __builtin_amdgcn_mfma_f32_16x16x32_f16(mwr[0][kk], hb0[kk], am0, 0,0,0);
      am1 = __builtin_amdgcn_mfma_f32_16x16x32_f16(mwr[1][kk], hb0[kk], am1, 0,0,0);
    }
    am0 = __builtin_amdgcn_mfma_f32_16x16x32_f16(mwr[0][4], dlb, am0, 0,0,0);
    am1 = __builtin_amdgcn_mfma_f32_16x16x32_f16(mwr[1][4], dlb, am1, 0,0,0);
    // ms = sigmoid(Mg + mod_b) * z  -> f16 b64 writes
    f16x4 msv;
    #pragma unroll
    for (int r=0;r<4;r++) msv[r] = (_Float16)(sigm(am0[r] + mbv[0][r]) * zv0[r]);
    *(f16x4*)((char*)MS_l + ((batch*512 + (2*w+0)*32 + kq*8) ^ swz)) = msv;
    #pragma unroll
    for (int r=0;r<4;r++) msv[r] = (_Float16)(sigm(am1[r] + mbv[1][r]) * zv1[r]);
    *(f16x4*)((char*)MS_l + ((batch*512 + (2*w+1)*32 + kq*8) ^ swz)) = msv;
    __syncthreads();   // MS ready
    // ---- main: G^T = Wih@MS^T + Whh@H^T + bias ----
    f32x4 acc[4];
    #pragma unroll
    for (int g=0; g<4; g++) acc[g] = bgv[g];
    #pragma unroll
    for (int kk=0; kk<8; kk++){
      if (kk < 6){
        #pragma unroll
        for (int g=0; g<4; g++)
          wb[(kk+2)%3][g] = WIHp[(((w + g*8)*8 + (kk+2))<<6) + lane];
      }
      f16x8 msb = *(const f16x8*)((const char*)MS_l + ((batch*512 + kk*64 + kq*16) ^ swz));
      #pragma unroll
      for (int g=0; g<4; g++)
        acc[g] = __builtin_amdgcn_mfma_f32_16x16x32_f16(wb[kk%3][g], msb, acc[g], 0,0,0);
    }
    #pragma unroll
    for (int kk=0; kk<4; kk++){
      #pragma unroll
      for (int g=0; g<4; g++)
        acc[g] = __builtin_amdgcn_mfma_f32_16x16x32_f16(whr[g][kk], hb0[kk], acc[g], 0,0,0);
    }
    // ---- cell update (pure registers; lane owns i/f/g/o for its 4 c-indices) ----
    #pragma unroll
    for (int r=0; r<4; r++){
      float cc = sigm(acc[1][r]) * cst[r] + sigm(acc[0][r]) * tanhft(acc[2][r]);
      cst[r] = cc;
      hv[r] = sigm(acc[3][r]) * tanhft(cc);
    }
    __syncthreads();   // all H_l reads (hb0) done before overwrite
    f16x4 hp;
    #pragma unroll
    for (int r=0;r<4;r++) hp[r] = (_Float16)hv[r];
    *(f16x4*)((char*)H_l + ((batch*256 + w*32 + kq*8) ^ swz)) = hp;
    __syncthreads();   // H ready for next step
  }
  // final h in f32 (exact) -> classifier
  *(f32x4*)((char*)MS_l + (batch*512 + w*64 + kq*16)) = hv;
  __syncthreads();
  if (tid < 128){
    int bb = tid >> 3, oo = tid & 7;
    const float* hf = (const float*)MS_l + bb*128;
    float a = cls_b[oo];
    #pragma unroll 16
    for (int k2=0; k2<HID_; k2++) a += hf[k2]*cls_w[oo*HID_+k2];
    out[(b0+bb)*8 + oo] = a;
  }
}

extern "C" void kernel_launch(void* const* d_in, const int* in_sizes, int n_in,
                              void* d_out, int out_size, void* d_ws, size_t ws_size,
                              hipStream_t stream){
  const float* x     = (const float*)d_in[0];
  const float* k_s   = (const float*)d_in[1];
  const float* k_a   = (const float*)d_in[2];
  const float* w1    = (const float*)d_in[3];
  const float* b1    = (const float*)d_in[4];
  const float* w2    = (const float*)d_in[5];
  const float* b2    = (const float*)d_in[6];
  const float* w3    = (const float*)d_in[7];
  const float* b3    = (const float*)d_in[8];
  const float* mod_w = (const float*)d_in[9];
  const float* mod_b = (const float*)d_in[10];
  const float* w_ih  = (const float*)d_in[11];
  const float* w_hh  = (const float*)d_in[12];
  const float* b_ih  = (const float*)d_in[13];
  const float* b_hh  = (const float*)d_in[14];
  const float* cls_w = (const float*)d_in[15];
  const float* cls_b = (const float*)d_in[16];
  float* outp = (float*)d_out;

  char* ws = (char*)d_ws;
  size_t o = 0;
  auto alloc = [&](size_t bytes){ size_t r = o; o = (o + bytes + 255) & ~(size_t)255; return r; };
  float*        Wq   = (float*)(ws + alloc((size_t)B_*S_*4));
  float*        Lq   = (float*)(ws + alloc((size_t)B_*S_*4));
  unsigned int* MM   = (unsigned int*)(ws + alloc(16));
  float*        DB   = (float*)(ws + alloc(B_*4));
  float*        LB   = (float*)(ws + alloc(B_*4));
  float*        WR1  = (float*)(ws + alloc((size_t)F_*3*C1_*4));
  float*        WR2  = (float*)(ws + alloc((size_t)C1_*3*C2_*4));
  float*        WR3  = (float*)(ws + alloc((size_t)C2_*3*C3_*4));
  __half*       WIHf = (__half*)(ws + alloc((size_t)32*8*512*2));
  __half*       WHHf = (__half*)(ws + alloc((size_t)32*4*512*2));
  __half*       MWf  = (__half*)(ws + alloc((size_t)16*5*512*2));
  float*        BG   = (float*)(ws + alloc(512*4));
  float*        Z1   = (float*)(ws + alloc((size_t)B_*C1_*S_*4));
  float*        Z2   = (float*)(ws + alloc((size_t)B_*C2_*S_*4));
  float*        ZT3  = (float*)(ws + alloc((size_t)B_*S_*C3_*4));
  (void)ws_size; (void)in_sizes; (void)n_in; (void)out_size;

  hipLaunchKernelGGL(k_init, dim3(1), dim3(64), 0, stream, MM);
  hipLaunchKernelGGL(k_queue1, dim3((B_*S_)/256), dim3(256), 0, stream, x, k_s, k_a, Wq, Lq, MM);
  hipLaunchKernelGGL(k_queue2, dim3(B_), dim3(256), 0, stream, Wq, Lq, MM, DB, LB);

  hipLaunchKernelGGL(k_repack_conv, dim3((F_*3*C1_+255)/256), dim3(256), 0, stream, w1, WR1, F_, C1_);
  hipLaunchKernelGGL(k_repack_conv, dim3((C1_*3*C2_+255)/256), dim3(256), 0, stream, w2, WR2, C1_, C2_);
  hipLaunchKernelGGL(k_repack_conv, dim3((C2_*3*C3_+255)/256), dim3(256), 0, stream, w3, WR3, C2_, C3_);
  {
    int N = 32*8*512 + 32*4*512 + 16*5*512 + 512;
    hipLaunchKernelGGL(k_repack_frags, dim3((N+255)/256), dim3(256), 0, stream,
                       mod_w, w_ih, w_hh, b_ih, b_hh, WIHf, WHHf, MWf, BG);
  }

  hipLaunchKernelGGL((k_conv<F_, C1_, 0>), dim3(S_/32, B_), dim3(256), 0, stream, x,  WR1, b1, Z1);
  hipLaunchKernelGGL(k_simam1, dim3(B_*C1_), dim3(256), 0, stream, Z1, DB, LB, C1_);
  hipLaunchKernelGGL((k_conv<C1_, C2_, 0>), dim3(S_/16, B_), dim3(256), 0, stream, Z1, WR2, b2, Z2);
  hipLaunchKernelGGL(k_simam1, dim3(B_*C2_), dim3(256), 0, stream, Z2, DB, LB, C2_);
  hipLaunchKernelGGL((k_conv<C2_, C3_, 1>), dim3(S_/8, B_), dim3(256), 0, stream, Z2, WR3, b3, ZT3);
  hipLaunchKernelGGL(k_simam2, dim3(B_), dim3(1024), 0, stream, ZT3, DB, LB);

  hipLaunchKernelGGL(k_lstm_mfma, dim3(B_/16), dim3(512), 0, stream,
                     ZT3, Wq, Lq, WIHf, WHHf, MWf, mod_b, BG, cls_w, cls_b, outp);
}